// Round 2
// 482.667 us; speedup vs baseline: 1.2026x; 1.2026x over previous
//
#include <hip/hip_runtime.h>

// ChannelAttentionModule (DANet channel attention) via bf16 MFMA.
// x: [B=8, C=512, N=96*96=9216] fp32, gamma scalar.
// v2 (resubmit; round-1 failure was infra): x -> bf16 once; gram/feat stage via
// global_load_lds (16B) into XOR-swizzled linear LDS; gram exploits Gram symmetry
// (10/16 tile pairs + mirrored atomics, split-K=8); feat B-tile = 8x4 register
// transpose from bf16. Fallback to the verified fp32-staged path if ws < 80 MiB.

typedef __attribute__((ext_vector_type(8))) short short8;   // 8 bf16 = 4 VGPR
typedef __attribute__((ext_vector_type(4))) float f32x4;    // MFMA C/D

#define GT 128      // gram/feat tile (M=N=128)
#define BK 64       // K-chunk (shorts)
#define LDA 72      // fallback-path LDS row stride (shorts)
#define NSPLIT 8    // new gram split-K
#define FBSPLIT 4   // fallback gram split-K

__device__ inline unsigned short f2bf(float f) {            // RNE (softmax only)
    unsigned u = __builtin_bit_cast(unsigned, f);
    u += 0x7fffu + ((u >> 16) & 1u);
    return (unsigned short)(u >> 16);
}
// pack two fp32 -> two truncated bf16 in ONE v_perm_b32
__device__ inline unsigned permpack(float a, float b) {
    return __builtin_amdgcn_perm(__builtin_bit_cast(unsigned, b),
                                 __builtin_bit_cast(unsigned, a), 0x07060302u);
}
// async 16B global -> LDS (linear dest: wave-uniform base + lane*16)
__device__ inline void gload_lds16(const short* g, short* l) {
    __builtin_amdgcn_global_load_lds(
        (const __attribute__((address_space(1))) void*)(g),
        (__attribute__((address_space(3))) void*)(l), 16, 0, 0);
}

// ---- convert: x fp32 -> ybf bf16 (truncate, matches MFMA input rounding) ----
__global__ __launch_bounds__(256) void tobf16_kernel(const float* __restrict__ x,
                                                     short* __restrict__ ybf) {
    const size_t total = (size_t)8 * 512 * 9216 / 8;   // uint4 units (8 bf16)
    const size_t stride = (size_t)gridDim.x * 256;
    for (size_t i = (size_t)blockIdx.x * 256 + threadIdx.x; i < total; i += stride) {
        const float4 a = ((const float4*)x)[2 * i];
        const float4 b = ((const float4*)x)[2 * i + 1];
        uint4 pv;
        pv.x = permpack(a.x, a.y);
        pv.y = permpack(a.z, a.w);
        pv.z = permpack(b.x, b.y);
        pv.w = permpack(b.z, b.w);
        ((uint4*)ybf)[i] = pv;
    }
}

// ---- GEMM1: att[b] += Y Y^T, symmetric tile pairs, split-K atomic ----------
// LDS layout: packed [128][64] shorts; 16B unit u of row r holds global unit
// u ^ (r&7) (involution; ds_read applies the same XOR -> conflict-free b128).
__global__ __launch_bounds__(256, 3) void gram_kernel2(const short* __restrict__ ybf,
                                                       float* __restrict__ att) {
    const int C = 512, N = 9216;
    __shared__ short As[GT * BK];
    __shared__ short Bs[GT * BK];
    const int pair = blockIdx.x;                       // 10 upper-tri pairs of 4x4
    const int i_ = (pair < 4) ? 0 : (pair < 7) ? 1 : (pair < 9) ? 2 : 3;
    const int j_ = pair - ((i_ == 0) ? 0 : (i_ == 1) ? 3 : (i_ == 2) ? 5 : 6);
    const int split = blockIdx.y, batch = blockIdx.z;
    const int c0 = i_ * GT, d0 = j_ * GT;
    const short* Y = ybf + (size_t)batch * C * N;
    const int t = threadIdx.x;
    const int w = t >> 6, l = t & 63;
    const int mw = (w >> 1) * 64, nw = (w & 1) * 64;
    const int lr = l & 15, lq = l >> 4;

    f32x4 acc[4][4] = {};
    const int kw = N / NSPLIT;                         // 1152 -> 18 iters of 64
    const int kbeg = split * kw;
    for (int k0 = kbeg; k0 < kbeg + kw; k0 += BK) {
        #pragma unroll
        for (int p = 0; p < 4; ++p) {                  // A tile: 1024 16B units
            const int u = t + p * 256;
            const int row = u >> 3;
            const int us = (u ^ row) & 7;              // pre-swizzled source unit
            gload_lds16(Y + (size_t)(c0 + row) * N + k0 + us * 8, &As[u * 8]);
        }
        #pragma unroll
        for (int p = 0; p < 4; ++p) {                  // B tile
            const int u = t + p * 256;
            const int row = u >> 3;
            const int us = (u ^ row) & 7;
            gload_lds16(Y + (size_t)(d0 + row) * N + k0 + us * 8, &Bs[u * 8]);
        }
        __syncthreads();                               // vmcnt(0) drain by compiler
        #pragma unroll
        for (int h = 0; h < 2; ++h) {
            short8 af[4], bf[4];
            #pragma unroll
            for (int i = 0; i < 4; i++) {
                const int r = mw + i * 16 + lr;
                af[i] = *(short8*)&As[r * BK + (((h * 4 + lq) ^ (r & 7)) * 8)];
            }
            #pragma unroll
            for (int j = 0; j < 4; j++) {
                const int r = nw + j * 16 + lr;
                bf[j] = *(short8*)&Bs[r * BK + (((h * 4 + lq) ^ (r & 7)) * 8)];
            }
            #pragma unroll
            for (int i = 0; i < 4; i++)
                #pragma unroll
                for (int j = 0; j < 4; j++)
                    acc[i][j] = __builtin_amdgcn_mfma_f32_16x16x32_bf16(af[i], bf[j], acc[i][j], 0, 0, 0);
        }
        __syncthreads();
    }
    // C/D layout: col = lane&15, row = (lane>>4)*4 + r. Mirror off-diag pairs.
    float* S = att + (size_t)batch * C * C;
    const bool mirror = (i_ != j_);
    #pragma unroll
    for (int i = 0; i < 4; i++)
        #pragma unroll
        for (int j = 0; j < 4; j++)
            #pragma unroll
            for (int r = 0; r < 4; r++) {
                const int row = c0 + mw + i * 16 + lq * 4 + r;
                const int col = d0 + nw + j * 16 + lr;
                const float v = acc[i][j][r];
                unsafeAtomicAdd(&S[(size_t)row * C + col], v);
                if (mirror) unsafeAtomicAdd(&S[(size_t)col * C + row], v);
            }
}

// ---- softmax over rows (len 512); emits bf16 in place ----------------------
__global__ __launch_bounds__(256) void softmax_kernel(float* __restrict__ att) {
    const int C = 512;
    float* S = att + (size_t)blockIdx.x * C;
    const int t = threadIdx.x;
    const float v0 = S[t], v1 = S[t + 256];

    float mn = fminf(v0, v1);
    #pragma unroll
    for (int off = 32; off > 0; off >>= 1) mn = fminf(mn, __shfl_xor(mn, off));
    __shared__ float redmin[4];
    const int wid = t >> 6, lane = t & 63;
    if (lane == 0) redmin[wid] = mn;
    __syncthreads();
    mn = fminf(fminf(redmin[0], redmin[1]), fminf(redmin[2], redmin[3]));

    const float e0 = expf(mn - v0), e1 = expf(mn - v1);
    float s = e0 + e1;
    #pragma unroll
    for (int off = 32; off > 0; off >>= 1) s += __shfl_xor(s, off);
    __shared__ float redsum[4];
    if (lane == 0) redsum[wid] = s;
    __syncthreads();
    s = redsum[0] + redsum[1] + redsum[2] + redsum[3];

    const float inv = 1.0f / s;
    unsigned short* S16 = (unsigned short*)S;
    S16[t] = f2bf(e0 * inv);
    S16[t + 256] = f2bf(e1 * inv);
}

// ---- GEMM2: out = gamma*(A Y) + x ------------------------------------------
// A: att bf16 rows via gload_lds (swizzled). B: Ybf [k][n] -> Bs[n][k] via
// 8kx4n register transpose (uint2 loads coalesced 256B, uint4 swizzled writes).
__global__ __launch_bounds__(256, 3) void feat_kernel2(const float* __restrict__ att,
                                                       const short* __restrict__ ybf,
                                                       const float* __restrict__ x,
                                                       const float* __restrict__ gamma,
                                                       float* __restrict__ out) {
    const int C = 512, N = 9216;
    __shared__ short As[GT * BK];
    __shared__ short Bs[GT * BK];
    const int b  = blockIdx.z;
    const int c0 = blockIdx.y * GT;
    const int n0 = blockIdx.x * GT;
    const short* Ab = (const short*)(att + (size_t)b * C * C);  // bf16 in low half, row stride 1024 shorts
    const short* Y = ybf + (size_t)b * C * N;
    const int t = threadIdx.x;
    const int w = t >> 6, l = t & 63;
    const int mw = (w >> 1) * 64, nw = (w & 1) * 64;
    const int lr = l & 15, lq = l >> 4;
    const int ng = t & 31, kg = t >> 5;   // B micro-tile: 8 k-rows x 4 n-cols

    f32x4 acc[4][4] = {};
    for (int k0 = 0; k0 < C; k0 += BK) {
        // A tile (async, swizzled)
        #pragma unroll
        for (int p = 0; p < 4; ++p) {
            const int u = t + p * 256;
            const int row = u >> 3;
            const int us = (u ^ row) & 7;
            gload_lds16(Ab + (size_t)(c0 + row) * 1024 + k0 + us * 8, &As[u * 8]);
        }
        // B tile: transpose 8x4 micro-tiles in registers
        {
            const short* pB = Y + (size_t)(k0 + kg * 8) * N + n0 + ng * 4;
            uint2 rr[8];
            #pragma unroll
            for (int r = 0; r < 8; ++r) rr[r] = *(const uint2*)(pB + (size_t)r * N);
            #pragma unroll
            for (int j = 0; j < 4; ++j) {
                const unsigned sel = (j & 1) ? 0x07060302u : 0x05040100u;
                unsigned w0, w1, w2, w3;
                if (j < 2) {
                    w0 = __builtin_amdgcn_perm(rr[1].x, rr[0].x, sel);
                    w1 = __builtin_amdgcn_perm(rr[3].x, rr[2].x, sel);
                    w2 = __builtin_amdgcn_perm(rr[5].x, rr[4].x, sel);
                    w3 = __builtin_amdgcn_perm(rr[7].x, rr[6].x, sel);
                } else {
                    w0 = __builtin_amdgcn_perm(rr[1].y, rr[0].y, sel);
                    w1 = __builtin_amdgcn_perm(rr[3].y, rr[2].y, sel);
                    w2 = __builtin_amdgcn_perm(rr[5].y, rr[4].y, sel);
                    w3 = __builtin_amdgcn_perm(rr[7].y, rr[6].y, sel);
                }
                const int nrow = ng * 4 + j;
                uint4 cv; cv.x = w0; cv.y = w1; cv.z = w2; cv.w = w3;
                *(uint4*)&Bs[nrow * BK + ((kg ^ (nrow & 7)) * 8)] = cv;
            }
        }
        __syncthreads();
        #pragma unroll
        for (int h = 0; h < 2; ++h) {
            short8 af[4], bf[4];
            #pragma unroll
            for (int i = 0; i < 4; i++) {
                const int r = mw + i * 16 + lr;
                af[i] = *(short8*)&As[r * BK + (((h * 4 + lq) ^ (r & 7)) * 8)];
            }
            #pragma unroll
            for (int j = 0; j < 4; j++) {
                const int r = nw + j * 16 + lr;
                bf[j] = *(short8*)&Bs[r * BK + (((h * 4 + lq) ^ (r & 7)) * 8)];
            }
            #pragma unroll
            for (int i = 0; i < 4; i++)
                #pragma unroll
                for (int j = 0; j < 4; j++)
                    acc[i][j] = __builtin_amdgcn_mfma_f32_16x16x32_bf16(af[i], bf[j], acc[i][j], 0, 0, 0);
        }
        __syncthreads();
    }

    const float g = gamma[0];
    float* O = out + (size_t)b * C * N;
    const float* X = x + (size_t)b * C * N;
    #pragma unroll
    for (int i = 0; i < 4; i++)
        #pragma unroll
        for (int j = 0; j < 4; j++)
            #pragma unroll
            for (int r = 0; r < 4; r++) {
                const int row = c0 + mw + i * 16 + lq * 4 + r;
                const int col = n0 + nw + j * 16 + lr;
                const size_t idx = (size_t)row * N + col;
                O[idx] = g * acc[i][j][r] + X[idx];
            }
}

// ======================= fallback path (previous verified) ==================
__global__ __launch_bounds__(256, 2) void gram_fb(const float* __restrict__ x,
                                                  float* __restrict__ att,
                                                  int C, int N) {
    __shared__ short As[GT * LDA];
    __shared__ short Bs[GT * LDA];
    const int bz = blockIdx.z;
    const int batch = bz & 7, split = bz >> 3;
    const int c0 = blockIdx.y * GT;
    const int d0 = blockIdx.x * GT;
    const float* Y = x + (size_t)batch * C * N;
    const int t = threadIdx.x;
    const int w = t >> 6, l = t & 63;
    const int mw = (w >> 1) * 64, nw = (w & 1) * 64;
    const int lr = l & 15, lq = l >> 4;

    f32x4 acc[4][4] = {};
    const int kbeg = split * (N / FBSPLIT);
    const int kend = kbeg + (N / FBSPLIT);
    for (int k0 = kbeg; k0 < kend; k0 += BK) {
        #pragma unroll
        for (int i = 0; i < 8; i++) {
            const int v = t + i * 256;
            const int row = v >> 4, kq = v & 15;
            float4 a = *(const float4*)(Y + (size_t)(c0 + row) * N + k0 + kq * 4);
            uint2 pa = make_uint2(permpack(a.x, a.y), permpack(a.z, a.w));
            *(uint2*)&As[row * LDA + kq * 4] = pa;
            float4 bv = *(const float4*)(Y + (size_t)(d0 + row) * N + k0 + kq * 4);
            uint2 pb = make_uint2(permpack(bv.x, bv.y), permpack(bv.z, bv.w));
            *(uint2*)&Bs[row * LDA + kq * 4] = pb;
        }
        __syncthreads();
        #pragma unroll
        for (int h = 0; h < 2; h++) {
            short8 af[4], bf[4];
            #pragma unroll
            for (int i = 0; i < 4; i++)
                af[i] = *(short8*)&As[(mw + i * 16 + lr) * LDA + h * 32 + lq * 8];
            #pragma unroll
            for (int j = 0; j < 4; j++)
                bf[j] = *(short8*)&Bs[(nw + j * 16 + lr) * LDA + h * 32 + lq * 8];
            #pragma unroll
            for (int i = 0; i < 4; i++)
                #pragma unroll
                for (int j = 0; j < 4; j++)
                    acc[i][j] = __builtin_amdgcn_mfma_f32_16x16x32_bf16(af[i], bf[j], acc[i][j], 0, 0, 0);
        }
        __syncthreads();
    }
    float* S = att + (size_t)batch * C * C;
    #pragma unroll
    for (int i = 0; i < 4; i++)
        #pragma unroll
        for (int j = 0; j < 4; j++)
            #pragma unroll
            for (int r = 0; r < 4; r++) {
                const int row = c0 + mw + i * 16 + lq * 4 + r;
                const int col = d0 + nw + j * 16 + lr;
                unsafeAtomicAdd(&S[(size_t)row * C + col], acc[i][j][r]);
            }
}

__global__ __launch_bounds__(256, 2) void feat_fb(const float* __restrict__ att,
                                                  const float* __restrict__ x,
                                                  const float* __restrict__ gamma,
                                                  float* __restrict__ out,
                                                  int C, int N) {
    __shared__ short As[GT * LDA];
    __shared__ short Bs[GT * LDA];
    const int b  = blockIdx.z;
    const int c0 = blockIdx.y * GT;
    const int n0 = blockIdx.x * GT;
    const short* Ab = (const short*)(att + (size_t)b * C * C);
    const float* Y = x + (size_t)b * C * N;
    const int t = threadIdx.x;
    const int w = t >> 6, l = t & 63;
    const int mw = (w >> 1) * 64, nw = (w & 1) * 64;
    const int lr = l & 15, lq = l >> 4;

    f32x4 acc[4][4] = {};
    for (int k0 = 0; k0 < C; k0 += BK) {
        #pragma unroll
        for (int i = 0; i < 4; i++) {
            const int v = t + i * 256;
            const int row = v >> 3, q = v & 7;
            uint4 va = *(const uint4*)(Ab + (size_t)(c0 + row) * 1024 + k0 + q * 8);
            *(uint4*)&As[row * LDA + q * 8] = va;
        }
        #pragma unroll
        for (int i = 0; i < 2; i++) {
            const int v = t + i * 256;
            const int kg = v & 15, ng = v >> 4;
            const float* p0 = Y + (size_t)(k0 + kg * 4) * N + n0 + ng * 4;
            float4 r0 = *(const float4*)(p0);
            float4 r1 = *(const float4*)(p0 + N);
            float4 r2 = *(const float4*)(p0 + 2 * (size_t)N);
            float4 r3 = *(const float4*)(p0 + 3 * (size_t)N);
            const float j0[4] = {r0.x, r1.x, r2.x, r3.x};
            const float j1[4] = {r0.y, r1.y, r2.y, r3.y};
            const float j2[4] = {r0.z, r1.z, r2.z, r3.z};
            const float j3[4] = {r0.w, r1.w, r2.w, r3.w};
            const float* cols[4] = {j0, j1, j2, j3};
            #pragma unroll
            for (int j = 0; j < 4; j++) {
                uint2 p = make_uint2(permpack(cols[j][0], cols[j][1]),
                                     permpack(cols[j][2], cols[j][3]));
                *(uint2*)&Bs[(ng * 4 + j) * LDA + kg * 4] = p;
            }
        }
        __syncthreads();
        #pragma unroll
        for (int h = 0; h < 2; h++) {
            short8 af[4], bf[4];
            #pragma unroll
            for (int i = 0; i < 4; i++)
                af[i] = *(short8*)&As[(mw + i * 16 + lr) * LDA + h * 32 + lq * 8];
            #pragma unroll
            for (int j = 0; j < 4; j++)
                bf[j] = *(short8*)&Bs[(nw + j * 16 + lr) * LDA + h * 32 + lq * 8];
            #pragma unroll
            for (int i = 0; i < 4; i++)
                #pragma unroll
                for (int j = 0; j < 4; j++)
                    acc[i][j] = __builtin_amdgcn_mfma_f32_16x16x32_bf16(af[i], bf[j], acc[i][j], 0, 0, 0);
        }
        __syncthreads();
    }

    const float g = gamma[0];
    float* O = out + (size_t)b * C * N;
    const float* X = x + (size_t)b * C * N;
    #pragma unroll
    for (int i = 0; i < 4; i++)
        #pragma unroll
        for (int j = 0; j < 4; j++)
            #pragma unroll
            for (int r = 0; r < 4; r++) {
                const int row = c0 + mw + i * 16 + lq * 4 + r;
                const int col = n0 + nw + j * 16 + lr;
                const size_t idx = (size_t)row * N + col;
                O[idx] = g * acc[i][j][r] + X[idx];
            }
}

extern "C" void kernel_launch(void* const* d_in, const int* in_sizes, int n_in,
                              void* d_out, int out_size, void* d_ws, size_t ws_size,
                              hipStream_t stream) {
    const int B = 8, C = 512, N = 96 * 96;
    const float* x     = (const float*)d_in[0];
    const float* gamma = (const float*)d_in[1];
    float* out = (float*)d_out;
    float* att = (float*)d_ws;                               // B*C*C fp32 = 8 MB
    const size_t attBytes = (size_t)B * C * C * sizeof(float);
    const size_t ybfBytes = (size_t)B * C * N * sizeof(short);  // 72 MB

    hipMemsetAsync(att, 0, attBytes, stream);

    dim3 blk(256);
    if (ws_size >= attBytes + ybfBytes) {
        short* ybf = (short*)((char*)d_ws + attBytes);
        tobf16_kernel<<<2048, blk, 0, stream>>>(x, ybf);
        gram_kernel2<<<dim3(10, NSPLIT, B), blk, 0, stream>>>(ybf, att);
        softmax_kernel<<<dim3(B * C), blk, 0, stream>>>(att);
        feat_kernel2<<<dim3(N / GT, C / GT, B), blk, 0, stream>>>(att, ybf, x, gamma, out);
    } else {
        gram_fb<<<dim3(C / GT, C / GT, B * FBSPLIT), blk, 0, stream>>>(x, att, C, N);
        softmax_kernel<<<dim3(B * C), blk, 0, stream>>>(att);
        feat_fb<<<dim3(N / GT, C / GT, B), blk, 0, stream>>>(att, x, gamma, out, C, N);
    }
}